// Round 9
// baseline (141.171 us; speedup 1.0000x reference)
//
#include <hip/hip_runtime.h>
#include <stdint.h>

#define BB 8
#define CC 256
#define NN 4096
#define KK 16

typedef float f32x4 __attribute__((ext_vector_type(4)));
typedef short bf16x8 __attribute__((ext_vector_type(8)));
typedef int   i32x4 __attribute__((ext_vector_type(4)));
typedef unsigned int u32x2 __attribute__((ext_vector_type(2)));

__device__ __forceinline__ ushort f2bf(float f) {
  union { float f; uint32_t u; } v; v.f = f;
  uint32_t r = v.u + 0x7FFFu + ((v.u >> 16) & 1u);   // RNE
  return (ushort)(r >> 16);
}
__device__ __forceinline__ float asf(uint32_t u) {
  union { uint32_t u; float f; } v; v.u = u; return v.f;
}
__device__ __forceinline__ float bf2f(ushort h) {
  union { uint32_t u; float f; } v; v.u = ((uint32_t)h) << 16;
  return v.f;
}

// K0: W[o][c] f32 -> Wfrag[kc][o][ks] bf16 (kc=c/32, ks=c%32). 64 blocks.
__global__ __launch_bounds__(256) void k_wprep(
    const float* __restrict__ W, ushort* __restrict__ Wfrag)
{
  const int t  = threadIdx.x;
  const int o  = blockIdx.x * 4 + (t >> 6);
  const int k0 = (t & 63) * 4;
  f32x4 v = __builtin_nontemporal_load((const f32x4*)(W + (size_t)o * CC + k0));
  ushort4 h;
  h.x = f2bf(v.x); h.y = f2bf(v.y); h.z = f2bf(v.z); h.w = f2bf(v.w);
  const int kc = k0 >> 5, ks = k0 & 31;
  *(ushort4*)(Wfrag + ((size_t)(kc * CC + o)) * 32 + ks) = h;
}

// K1: y = W @ x computed BEFORE the gather (linearity: conv and neighbor-sum
// commute). Reads x[b][c][n] f32 directly from HBM, transposes+converts to
// bf16 in LDS, MFMA against Wfrag, writes yT[b][n][o] bf16 (no bias/relu yet).
// b = bid&7: batch b's yT slab is produced on XCD b (2.1 MB, L2-resident).
__global__ __launch_bounds__(256) void k_conv(
    const float* __restrict__ x, const ushort* __restrict__ Wfrag,
    ushort* __restrict__ yT)
{
  __shared__ float  ftile[64][36];         // 64 c x 32 n f32 subtile (padded)
  __shared__ ushort xlds[32][264];         // 32 n x 256 c bf16 (528B stride)
  const int bid = blockIdx.x;              // 1024 blocks
  const int b   = bid & 7;
  const int n0  = (bid >> 3) * 32;
  const int t    = threadIdx.x;
  const int wave = t >> 6, lane = t & 63;

  // Stage 4 c-subtiles: read 64c x 32n f32 coalesced, transpose via LDS,
  // pack bf16 into xlds[n][c].
  const int r  = t >> 2;                   // c-local 0..63
  const int cs = (t & 3) * 4;              // n-offset: loads at cs, cs+16
  const int nl = t >> 3;                   // n-local 0..31
  const int cl = (t & 7) * 8;              // c-offset 0..56
  #pragma unroll
  for (int cb = 0; cb < 4; ++cb) {
    const float* xp = x + ((size_t)(b * CC + cb * 64 + r)) * NN + n0 + cs;
    f32x4 v0 = __builtin_nontemporal_load((const f32x4*)xp);
    f32x4 v1 = __builtin_nontemporal_load((const f32x4*)(xp + 16));
    __syncthreads();                       // prev iter's ftile reads done
    *(f32x4*)&ftile[r][cs]      = v0;
    *(f32x4*)&ftile[r][cs + 16] = v1;
    __syncthreads();
    union { ushort s[8]; uint4 q; } pk;
    #pragma unroll
    for (int i = 0; i < 8; ++i) pk.s[i] = f2bf(ftile[cl + i][nl]);
    *(uint4*)&xlds[nl][cb * 64 + cl] = pk.q;
  }
  __syncthreads();

  // GEMM: wave w -> o in [w*64, w*64+64), all 32 n.
  f32x4 acc[4][2];
  #pragma unroll
  for (int m = 0; m < 4; ++m)
    #pragma unroll
    for (int nn = 0; nn < 2; ++nn) acc[m][nn] = (f32x4){0.f, 0.f, 0.f, 0.f};

  const int lrow = lane & 15;
  const int kgrp = lane >> 4;
  const int o0   = wave * 64;

  #pragma unroll
  for (int kc = 0; kc < 8; ++kc) {
    const int c2 = kgrp * 8;
    bf16x8 afr[4], bfr[2];
    #pragma unroll
    for (int m = 0; m < 4; ++m) {
      const uint32_t aoff = (uint32_t)(kc * CC + o0 + m * 16 + lrow) * 32 + c2;
      afr[m] = *(const bf16x8*)(Wfrag + aoff);
    }
    #pragma unroll
    for (int nn = 0; nn < 2; ++nn)
      bfr[nn] = *(const bf16x8*)&xlds[nn * 16 + lrow][kc * 32 + c2];
    #pragma unroll
    for (int m = 0; m < 4; ++m)
      #pragma unroll
      for (int nn = 0; nn < 2; ++nn)
        acc[m][nn] = __builtin_amdgcn_mfma_f32_16x16x32_bf16(
            afr[m], bfr[nn], acc[m][nn], 0, 0, 0);
  }

  // Epilogue: D col=lane&15 (n), row=kgrp*4+r (o-local). Write yT bf16.
  #pragma unroll
  for (int m = 0; m < 4; ++m) {
    #pragma unroll
    for (int nn = 0; nn < 2; ++nn) {
      const int n = n0 + nn * 16 + lrow;
      const int o = o0 + m * 16 + kgrp * 4;
      uint2 pk2;
      pk2.x = (uint32_t)f2bf(acc[m][nn][0]) | ((uint32_t)f2bf(acc[m][nn][1]) << 16);
      pk2.y = (uint32_t)f2bf(acc[m][nn][2]) | ((uint32_t)f2bf(acc[m][nn][3]) << 16);
      *(uint2*)(yT + (((size_t)b * NN + n) << 8) + o) = pk2;  // stays in XCD-b L2
    }
  }
}

// K2: out[b][o][n] = relu((1+eps)*y[n][o] + sum_k y[idx[n,k]][o] + bias[o]).
// Row-per-wave gathers (o-contiguous 512B rows, saddr form); result staged in
// f32 LDS tile res[n][o]; write-out transposed -> out coalesced along n.
__global__ __launch_bounds__(256) void k_gout(
    const ushort* __restrict__ yT, const int* __restrict__ edge0,
    const float* __restrict__ eps, const float* __restrict__ bias,
    float* __restrict__ out)
{
  __shared__ float res[32][264];           // [n-local][o] f32
  const int bid = blockIdx.x;              // 1024 blocks
  const int b   = bid & 7;
  const int n0  = (bid >> 3) * 32;
  const int t    = threadIdx.x;
  const int wave = t >> 6, lane = t & 63;
  const float epsv = 1.0f + eps[0];
  const ushort* yb = yT + (size_t)b * NN * CC;
  const int c4 = lane * 4;                 // o-channels [c4, c4+4) per lane
  const f32x4 bv = *(const f32x4*)(bias + c4);

  #pragma unroll
  for (int i = 0; i < 8; ++i) {
    const int nl = wave * 8 + i;
    const int n  = n0 + nl;
    const i32x4* epv = (const i32x4*)(edge0 + ((size_t)b * NN + n) * KK);
    i32x4 e0 = __builtin_nontemporal_load(epv + 0);
    i32x4 e1 = __builtin_nontemporal_load(epv + 1);
    i32x4 e2 = __builtin_nontemporal_load(epv + 2);
    i32x4 e3 = __builtin_nontemporal_load(epv + 3);
    u32x2 sv = *(const u32x2*)(yb + ((size_t)n << 8) + c4);

    const int js[16] = {e0.x, e0.y, e0.z, e0.w, e1.x, e1.y, e1.z, e1.w,
                        e2.x, e2.y, e2.z, e2.w, e3.x, e3.y, e3.z, e3.w};
    f32x4 acc = (f32x4){0.f, 0.f, 0.f, 0.f};
    #pragma unroll
    for (int k = 0; k < KK; ++k) {
      const int jr = __builtin_amdgcn_readfirstlane(js[k]);  // wave-uniform
      const ushort* rp = yb + ((size_t)jr << 8);             // SGPR base
      u32x2 g = *(const u32x2*)(rp + c4);                    // saddr + voffset
      acc += (f32x4){asf(g.x << 16), asf(g.x & 0xffff0000u),
                     asf(g.y << 16), asf(g.y & 0xffff0000u)};
    }
    acc += (f32x4){asf(sv.x << 16), asf(sv.x & 0xffff0000u),
                   asf(sv.y << 16), asf(sv.y & 0xffff0000u)} * epsv;
    acc += bv;
    #pragma unroll
    for (int j = 0; j < 4; ++j) acc[j] = acc[j] > 0.f ? acc[j] : 0.f;
    *(f32x4*)&res[nl][c4] = acc;
  }
  __syncthreads();

  // Write-out: thread t owns o-row t; 32 n values, contiguous f32x4 stores.
  float* op = out + ((size_t)b * CC + t) * NN + n0;
  #pragma unroll
  for (int ch = 0; ch < 8; ++ch) {
    f32x4 v;
    #pragma unroll
    for (int j = 0; j < 4; ++j) v[j] = res[ch * 4 + j][t];
    *(f32x4*)(op + ch * 4) = v;            // plain store: L2 merges lines
  }
}

extern "C" void kernel_launch(void* const* d_in, const int* in_sizes, int n_in,
                              void* d_out, int out_size, void* d_ws, size_t ws_size,
                              hipStream_t stream) {
  const float* x    = (const float*)d_in[0];
  const int*   edge = (const int*)d_in[1];   // [2][B][N][K] int32, plane 0 used
  const float* eps  = (const float*)d_in[2];
  const float* W    = (const float*)d_in[3];
  const float* bias = (const float*)d_in[4];
  float* out = (float*)d_out;

  ushort* yT    = (ushort*)d_ws;                         // [B][N][C] bf16, 16.8 MB
  ushort* Wfrag = yT + (size_t)BB * NN * CC;             // [8][C][32] bf16, 128 KB

  k_wprep<<<CC / 4, 256, 0, stream>>>(W, Wfrag);

  k_conv<<<BB * (NN / 32), 256, 0, stream>>>(x, Wfrag, yT);

  k_gout<<<BB * (NN / 32), 256, 0, stream>>>(yT, edge, eps, bias, out);
}